// Round 1
// baseline (197.213 us; speedup 1.0000x reference)
//
#include <hip/hip_runtime.h>
#include <hip/hip_bf16.h>

// CorrelationLayerCosineSimilarity: out[b,d,h,w] = dot_c(x1[b,c,h,w], x2p[b,c,h,w+d])
//                                               / max(n1[b,h,w]*n2p[b,h,w+d], 1e-6)
// x2p = x2 zero-padded by 40 on the width axis. B=4,C=256,H=128,W=256,D=41.
//
// Design (round 1):
//  - grid = 512 blocks, one per (b,h). block = 512 threads = 8 waves.
//  - wave = (half, dg): half in {0,1} owns channels [128*half, 128*half+128);
//    dg in {0..3} owns d-range [10*dg, 10*dg+10] (11 wide, overlapping at 10/20/30;
//    duplicates computed but stored once).
//  - thread: lane l owns w = 4l..4l+3; register sliding window of 16 x2 floats
//    (4x ds_read_b128) feeds 44 FMAs per channel -> LDS traffic ~2.7 GB total.
//  - x1/x2 rows staged in LDS in chunks of 8 channels per half (16 rows/iter).
//  - norms accumulated by dg==0 waves; c-half dot reduction via LDS overlay.

#define B_   4
#define C_   256
#define H_   128
#define W_   256
#define ND_  41
#define HW_  (H_ * W_)        // 32768
#define CHW_ (C_ * HW_)       // 8388608
#define EPS_ 1e-6f

__device__ __forceinline__ float4 ld4(const float* p) { return *(const float4*)p; }

template<int OFS, bool NORM>
__device__ __forceinline__ void cc_compute(const float* s1row, const float* s2row,
                                           int w0, int a0,
                                           float (&acc)[11][4], float (&ssq1)[4],
                                           float (&ssq2)[4]) {
  float4 xv = ld4(s1row + w0);
  float xq[4] = {xv.x, xv.y, xv.z, xv.w};
  float4 wv0 = ld4(s2row + a0);
  float4 wv1 = ld4(s2row + a0 + 4);
  float4 wv2 = ld4(s2row + a0 + 8);
  float4 wv3 = ld4(s2row + a0 + 12);
  float win[16] = {wv0.x, wv0.y, wv0.z, wv0.w, wv1.x, wv1.y, wv1.z, wv1.w,
                   wv2.x, wv2.y, wv2.z, wv2.w, wv3.x, wv3.y, wv3.z, wv3.w};
  if (NORM) {
#pragma unroll
    for (int j = 0; j < 4; ++j) {
      ssq1[j] += xq[j] * xq[j];
      ssq2[j] += win[j] * win[j];   // valid: OFS==0 path has a0 == w0
    }
  }
#pragma unroll
  for (int d = 0; d < 11; ++d) {
#pragma unroll
    for (int j = 0; j < 4; ++j) {
      acc[d][j] += xq[j] * win[OFS + d + j];   // OFS+d+j <= 2+10+3 = 15
    }
  }
}

template<int OFS>
__device__ __forceinline__ void finalize(const float (&acc)[11][4],
                                         const float* n1p, const float* n2p,
                                         int w0, int a0, int d_lo, float* outp) {
  float4 nv = ld4(n1p + w0);
  float nq[4] = {nv.x, nv.y, nv.z, nv.w};
  float4 m0 = ld4(n2p + a0);
  float4 m1 = ld4(n2p + a0 + 4);
  float4 m2 = ld4(n2p + a0 + 8);
  float4 m3 = ld4(n2p + a0 + 12);
  float nw[16] = {m0.x, m0.y, m0.z, m0.w, m1.x, m1.y, m1.z, m1.w,
                  m2.x, m2.y, m2.z, m2.w, m3.x, m3.y, m3.z, m3.w};
#pragma unroll
  for (int d = 0; d < 11; ++d) {
    if (d >= d_lo) {   // wave-uniform; skips duplicated boundary d for dg>0
      float4 o;
      o.x = acc[d][0] / fmaxf(nq[0] * nw[OFS + d + 0], EPS_);
      o.y = acc[d][1] / fmaxf(nq[1] * nw[OFS + d + 1], EPS_);
      o.z = acc[d][2] / fmaxf(nq[2] * nw[OFS + d + 2], EPS_);
      o.w = acc[d][3] / fmaxf(nq[3] * nw[OFS + d + 3], EPS_);
      *(float4*)(outp + d * HW_) = o;
    }
  }
}

__global__ __launch_bounds__(512)
void corr_cos_kernel(const float* __restrict__ x1, const float* __restrict__ x2,
                     float* __restrict__ out) {
  // staging buffers overlaid with the epilogue reduction buffer
  __shared__ __align__(16) float s_u[11264];   // max(16*256+16*296=8832, 4*64*44=11264)
  __shared__ float sq1[2][256];
  __shared__ float sq2[2][256];
  __shared__ float n1s[256];
  __shared__ __align__(16) float n2s[304];

  float* s1  = s_u;               // [16][256] x1 rows
  float* s2  = s_u + 16 * 256;    // [16][296] x2 rows (cols 256..295 zeroed)
  float* red = s_u;               // epilogue: [4 dg][64 lane][44]

  const int tid  = threadIdx.x;
  const int lane = tid & 63;
  const int wv   = tid >> 6;
  const int half = wv >> 2;       // c-half
  const int dg   = wv & 3;        // d-group
  const int d0   = dg * 10;
  const int w0   = lane * 4;
  const int a0   = w0 + (d0 & ~3);   // 16B-aligned window base

  const int r = blockIdx.x;
  const int b = r >> 7;           // H_ = 128
  const int h = r & (H_ - 1);

  const float* X1 = x1 + b * CHW_ + h * W_;
  const float* X2 = x2 + b * CHW_ + h * W_;

  float acc[11][4];
#pragma unroll
  for (int d = 0; d < 11; ++d)
#pragma unroll
    for (int j = 0; j < 4; ++j) acc[d][j] = 0.f;
  float ssq1[4] = {0.f, 0.f, 0.f, 0.f};
  float ssq2[4] = {0.f, 0.f, 0.f, 0.f};

  for (int it = 0; it < 16; ++it) {
    __syncthreads();   // previous compute done before overwriting stage buffers
    // ---- stage 16 channel rows: 8 per half. x1: 16*64 quads, x2: 16*74 quads ----
    auto stage = [&](int q) {
      if (q < 1024) {
        int row = q >> 6, j = q & 63;
        int c = it * 8 + ((row & 8) << 4) + (row & 7);
        *(float4*)(s1 + row * 256 + 4 * j) = ld4(X1 + c * HW_ + 4 * j);
      } else {
        int qq = q - 1024;
        int row = qq / 74, j = qq - row * 74;
        int c = it * 8 + ((row & 8) << 4) + (row & 7);
        float4 v = make_float4(0.f, 0.f, 0.f, 0.f);
        if (j < 64) v = ld4(X2 + c * HW_ + 4 * j);
        *(float4*)(s2 + row * 296 + 4 * j) = v;
      }
    };
    stage(tid);
    stage(tid + 512);
    stage(tid + 1024);
    stage(tid + 1536);
    if (tid < 2208 - 2048) stage(tid + 2048);
    __syncthreads();

    // ---- compute 8 channels for this wave's half ----
    const float* s1h = s1 + half * (8 * 256);
    const float* s2h = s2 + half * (8 * 296);
    if (dg == 0) {
      for (int cc = 0; cc < 8; ++cc)
        cc_compute<0, true>(s1h + cc * 256, s2h + cc * 296, w0, a0, acc, ssq1, ssq2);
    } else if (dg == 1) {
      for (int cc = 0; cc < 8; ++cc)
        cc_compute<2, false>(s1h + cc * 256, s2h + cc * 296, w0, a0, acc, ssq1, ssq2);
    } else if (dg == 2) {
      for (int cc = 0; cc < 8; ++cc)
        cc_compute<0, false>(s1h + cc * 256, s2h + cc * 296, w0, a0, acc, ssq1, ssq2);
    } else {
      for (int cc = 0; cc < 8; ++cc)
        cc_compute<2, false>(s1h + cc * 256, s2h + cc * 296, w0, a0, acc, ssq1, ssq2);
    }
  }

  // ---- epilogue ----
  __syncthreads();   // all reads of s1/s2 done; safe to overlay red
  if (dg == 0) {
#pragma unroll
    for (int j = 0; j < 4; ++j) {
      sq1[half][w0 + j] = ssq1[j];
      sq2[half][w0 + j] = ssq2[j];
    }
  }
  if (half == 1) {
    float* rp = red + (dg * 64 + lane) * 44;
#pragma unroll
    for (int d = 0; d < 11; ++d)
      *(float4*)(rp + d * 4) = make_float4(acc[d][0], acc[d][1], acc[d][2], acc[d][3]);
  }
  __syncthreads();
  if (half == 0) {
    const float* rp = red + (dg * 64 + lane) * 44;
#pragma unroll
    for (int d = 0; d < 11; ++d) {
      float4 v = ld4(rp + d * 4);
      acc[d][0] += v.x; acc[d][1] += v.y; acc[d][2] += v.z; acc[d][3] += v.w;
    }
    n1s[tid] = sqrtf(sq1[0][tid] + sq1[1][tid]);   // half==0 -> tid in [0,256)
    n2s[tid] = sqrtf(sq2[0][tid] + sq2[1][tid]);
  } else if (tid < 304) {
    n2s[tid] = 0.f;   // zero-padded cols 256..303
  }
  __syncthreads();

  if (half == 0) {
    float* outp = out + (b * ND_ + d0) * HW_ + h * W_ + w0;
    int d_lo = (dg == 0) ? 0 : 1;   // boundary d duplicated across dg; store once
    if (dg == 0)      finalize<0>(acc, n1s, n2s, w0, a0, d_lo, outp);
    else if (dg == 1) finalize<2>(acc, n1s, n2s, w0, a0, d_lo, outp);
    else if (dg == 2) finalize<0>(acc, n1s, n2s, w0, a0, d_lo, outp);
    else              finalize<2>(acc, n1s, n2s, w0, a0, d_lo, outp);
  }
}

extern "C" void kernel_launch(void* const* d_in, const int* in_sizes, int n_in,
                              void* d_out, int out_size, void* d_ws, size_t ws_size,
                              hipStream_t stream) {
  const float* x1 = (const float*)d_in[0];
  const float* x2 = (const float*)d_in[1];
  float* out = (float*)d_out;
  dim3 grid(B_ * H_);
  dim3 block(512);
  hipLaunchKernelGGL(corr_cos_kernel, grid, block, 0, stream, x1, x2, out);
}

// Round 2
// 142.172 us; speedup vs baseline: 1.3871x; 1.3871x over previous
//
#include <hip/hip_runtime.h>
#include <hip/hip_bf16.h>

// CorrelationLayerCosineSimilarity: out[b,d,h,w] = dot_c(x1[b,c,h,w], x2p[b,c,h,w+d])
//                                               / max(n1[b,h,w]*n2p[b,h,w+d], 1e-6)
// x2p = x2 zero-padded by 40 on width. B=4,C=256,H=128,W=256,D=41.
//
// Round 2: async pipeline.
//  - global_load_lds width=16 staging: wave stages whole 256-float rows
//    (64 lanes x 16B = 1 row, wave-uniform LDS dest -> linear, HW-legal).
//  - double-buffered 2-phase: issue stage(t+1) before compute(t); ONE
//    __syncthreads (drains vmcnt+lgkm) per iteration (was 2 + sync staging).
//  - x2 pad cols (256..295) pre-zeroed once per buffer; gload writes 0..255 only.
//  - rest of the structure unchanged from round 1 (passed, absmax 9.8e-4).

#define B_   4
#define C_   256
#define H_   128
#define W_   256
#define ND_  41
#define HW_  (H_ * W_)        // 32768
#define CHW_ (C_ * HW_)       // 8388608
#define EPS_ 1e-6f

#define S1_FLOATS (16 * 256)                       // 4096 per buffer
#define S2_FLOATS (16 * 296)                       // 4736 per buffer
#define STAGE_FLOATS (2 * S1_FLOATS + 2 * S2_FLOATS)   // 17664 floats = 69 KB

__device__ __forceinline__ float4 ld4(const float* p) { return *(const float4*)p; }

__device__ __forceinline__ void gload16(const float* g, float* l) {
  __builtin_amdgcn_global_load_lds(
      (const __attribute__((address_space(1))) unsigned int*)(uintptr_t)g,
      (__attribute__((address_space(3))) unsigned int*)(uintptr_t)l,
      16, 0, 0);
}

template<int OFS, bool NORM>
__device__ __forceinline__ void cc_compute(const float* s1row, const float* s2row,
                                           int w0, int a0,
                                           float (&acc)[11][4], float (&ssq1)[4],
                                           float (&ssq2)[4]) {
  float4 xv = ld4(s1row + w0);
  float xq[4] = {xv.x, xv.y, xv.z, xv.w};
  float4 wv0 = ld4(s2row + a0);
  float4 wv1 = ld4(s2row + a0 + 4);
  float4 wv2 = ld4(s2row + a0 + 8);
  float4 wv3 = ld4(s2row + a0 + 12);
  float win[16] = {wv0.x, wv0.y, wv0.z, wv0.w, wv1.x, wv1.y, wv1.z, wv1.w,
                   wv2.x, wv2.y, wv2.z, wv2.w, wv3.x, wv3.y, wv3.z, wv3.w};
  if (NORM) {
#pragma unroll
    for (int j = 0; j < 4; ++j) {
      ssq1[j] += xq[j] * xq[j];
      ssq2[j] += win[j] * win[j];   // valid: OFS==0 path has a0 == w0
    }
  }
#pragma unroll
  for (int d = 0; d < 11; ++d) {
#pragma unroll
    for (int j = 0; j < 4; ++j) {
      acc[d][j] += xq[j] * win[OFS + d + j];   // OFS+d+j <= 15
    }
  }
}

template<int OFS>
__device__ __forceinline__ void finalize(const float (&acc)[11][4],
                                         const float* n1p, const float* n2p,
                                         int w0, int a0, int d_lo, float* outp) {
  float4 nv = ld4(n1p + w0);
  float nq[4] = {nv.x, nv.y, nv.z, nv.w};
  float4 m0 = ld4(n2p + a0);
  float4 m1 = ld4(n2p + a0 + 4);
  float4 m2 = ld4(n2p + a0 + 8);
  float4 m3 = ld4(n2p + a0 + 12);
  float nw[16] = {m0.x, m0.y, m0.z, m0.w, m1.x, m1.y, m1.z, m1.w,
                  m2.x, m2.y, m2.z, m2.w, m3.x, m3.y, m3.z, m3.w};
#pragma unroll
  for (int d = 0; d < 11; ++d) {
    if (d >= d_lo) {   // wave-uniform; skips duplicated boundary d for dg>0
      float4 o;
      o.x = acc[d][0] / fmaxf(nq[0] * nw[OFS + d + 0], EPS_);
      o.y = acc[d][1] / fmaxf(nq[1] * nw[OFS + d + 1], EPS_);
      o.z = acc[d][2] / fmaxf(nq[2] * nw[OFS + d + 2], EPS_);
      o.w = acc[d][3] / fmaxf(nq[3] * nw[OFS + d + 3], EPS_);
      *(float4*)(outp + d * HW_) = o;
    }
  }
}

__global__ __launch_bounds__(512)
void corr_cos_kernel(const float* __restrict__ x1, const float* __restrict__ x2,
                     float* __restrict__ out) {
  // [buf0 s1][buf1 s1][buf0 s2][buf1 s2]; epilogue red overlays (needs 11264 fl)
  __shared__ __align__(16) float s_u[STAGE_FLOATS];
  __shared__ float sq1[2][256];
  __shared__ float sq2[2][256];
  __shared__ float n1s[256];
  __shared__ __align__(16) float n2s[304];

#define S1P(bi) (s_u + (bi) * S1_FLOATS)
#define S2P(bi) (s_u + 2 * S1_FLOATS + (bi) * S2_FLOATS)

  const int tid  = threadIdx.x;
  const int lane = tid & 63;
  const int wv   = tid >> 6;
  const int half = wv >> 2;       // c-half
  const int dg   = wv & 3;        // d-group
  const int d0   = dg * 10;
  const int w0   = lane * 4;
  const int a0   = w0 + (d0 & ~3);   // 16B-aligned window base

  const int r = blockIdx.x;
  const int b = r >> 7;           // H_ = 128
  const int h = r & (H_ - 1);

  const float* X1 = x1 + b * CHW_ + h * W_;
  const float* X2 = x2 + b * CHW_ + h * W_;

  // issue 4 async row-loads for tile `it` into buffer `bi` (this wave's share)
  auto stage = [&](int bi, int it) {
    if (wv < 4) {
      float* s1d = S1P(bi);
#pragma unroll
      for (int k = 0; k < 4; ++k) {
        int row = wv * 4 + k;
        int c = it * 8 + ((row & 8) << 4) + (row & 7);
        gload16(X1 + c * HW_ + 4 * lane, s1d + row * 256);
      }
    } else {
      float* s2d = S2P(bi);
#pragma unroll
      for (int k = 0; k < 4; ++k) {
        int row = (wv - 4) * 4 + k;
        int c = it * 8 + ((row & 8) << 4) + (row & 7);
        gload16(X2 + c * HW_ + 4 * lane, s2d + row * 296);
      }
    }
  };

  float acc[11][4];
#pragma unroll
  for (int d = 0; d < 11; ++d)
#pragma unroll
    for (int j = 0; j < 4; ++j) acc[d][j] = 0.f;
  float ssq1[4] = {0.f, 0.f, 0.f, 0.f};
  float ssq2[4] = {0.f, 0.f, 0.f, 0.f};

  // ---- prologue: zero x2 pad cols of both buffers, stage tile 0 ----
  for (int i = tid; i < 2 * 16 * 40; i += 512) {
    int bi  = i / 640;
    int rem = i - bi * 640;
    int row = rem / 40;
    int col = rem - row * 40;
    S2P(bi)[row * 296 + 256 + col] = 0.f;
  }
  stage(0, 0);
  __syncthreads();   // drains vmcnt (gload) + lgkm (pad zeroing)

  // ---- main loop: 2-phase double-buffered pipeline, 1 barrier/iter ----
  int cur = 0;
  for (int it = 0; it < 16; ++it) {
    if (it < 15) stage(cur ^ 1, it + 1);   // async loads overlap compute below
    const float* s1h = S1P(cur) + half * (8 * 256);
    const float* s2h = S2P(cur) + half * (8 * 296);
    if (dg == 0) {
      for (int cc = 0; cc < 8; ++cc)
        cc_compute<0, true>(s1h + cc * 256, s2h + cc * 296, w0, a0, acc, ssq1, ssq2);
    } else if (dg == 1) {
      for (int cc = 0; cc < 8; ++cc)
        cc_compute<2, false>(s1h + cc * 256, s2h + cc * 296, w0, a0, acc, ssq1, ssq2);
    } else if (dg == 2) {
      for (int cc = 0; cc < 8; ++cc)
        cc_compute<0, false>(s1h + cc * 256, s2h + cc * 296, w0, a0, acc, ssq1, ssq2);
    } else {
      for (int cc = 0; cc < 8; ++cc)
        cc_compute<2, false>(s1h + cc * 256, s2h + cc * 296, w0, a0, acc, ssq1, ssq2);
    }
    __syncthreads();   // next tile staged + this tile's reads done
    cur ^= 1;
  }

  // ---- epilogue (last loop barrier already passed: safe to overlay red) ----
  float* red = s_u;   // [4 dg][64 lane][44] = 11264 floats <= STAGE_FLOATS
  if (dg == 0) {
    *(float4*)&sq1[half][w0] = make_float4(ssq1[0], ssq1[1], ssq1[2], ssq1[3]);
    *(float4*)&sq2[half][w0] = make_float4(ssq2[0], ssq2[1], ssq2[2], ssq2[3]);
  }
  if (half == 1) {
    float* rp = red + (dg * 64 + lane) * 44;
#pragma unroll
    for (int d = 0; d < 11; ++d)
      *(float4*)(rp + d * 4) = make_float4(acc[d][0], acc[d][1], acc[d][2], acc[d][3]);
  }
  __syncthreads();
  if (half == 0) {
    const float* rp = red + (dg * 64 + lane) * 44;
#pragma unroll
    for (int d = 0; d < 11; ++d) {
      float4 v = ld4(rp + d * 4);
      acc[d][0] += v.x; acc[d][1] += v.y; acc[d][2] += v.z; acc[d][3] += v.w;
    }
    n1s[tid] = sqrtf(sq1[0][tid] + sq1[1][tid]);   // half==0 -> tid in [0,256)
    n2s[tid] = sqrtf(sq2[0][tid] + sq2[1][tid]);
  } else if (tid < 304) {
    n2s[tid] = 0.f;   // zero-padded cols 256..303
  }
  __syncthreads();

  if (half == 0) {
    float* outp = out + (b * ND_ + d0) * HW_ + h * W_ + w0;
    int d_lo = (dg == 0) ? 0 : 1;   // boundary d duplicated across dg; store once
    if (dg == 0)      finalize<0>(acc, n1s, n2s, w0, a0, d_lo, outp);
    else if (dg == 1) finalize<2>(acc, n1s, n2s, w0, a0, d_lo, outp);
    else if (dg == 2) finalize<0>(acc, n1s, n2s, w0, a0, d_lo, outp);
    else              finalize<2>(acc, n1s, n2s, w0, a0, d_lo, outp);
  }
}

extern "C" void kernel_launch(void* const* d_in, const int* in_sizes, int n_in,
                              void* d_out, int out_size, void* d_ws, size_t ws_size,
                              hipStream_t stream) {
  const float* x1 = (const float*)d_in[0];
  const float* x2 = (const float*)d_in[1];
  float* out = (float*)d_out;
  dim3 grid(B_ * H_);
  dim3 block(512);
  hipLaunchKernelGGL(corr_cos_kernel, grid, block, 0, stream, x1, x2, out);
}

// Round 3
// 61.980 us; speedup vs baseline: 3.1819x; 2.2939x over previous
//
#include <hip/hip_runtime.h>
#include <hip/hip_bf16.h>

// CorrelationLayerCosineSimilarity via banded bf16 MFMA GEMM.
// Per (b,h): Out[w,d] = sum_c x1[c,w]*x2p[c,w+d] / max(n1[w]*n2[w+d], 1e-6)
// B=4,C=256,H=128,W=256,D=41.  Out tiles: 16 w-tiles x 4 col-tiles of 16.
// 512 blocks (one per b,h) x 512 thr (8 waves). Wave v owns wt in {v, v+8},
// each wt x 4 ctiles -> 8 acc tiles (f32x4 each). K = 256 = 8 steps of 32.
//
// LDS (47040 B): A_lds[w 0..255][kc 0..31] bf16, row=80B (4x16B slots + 1 pad
// slot, k-slot s of row w lives at physical slot (s+w)%5 -> conflict-free
// b128 frag reads).  B_lds[w' 0..303][kc] same (rows 256..303 zeroed once).
// Staging: reg-based (fp32 loads -> RNE bf16 -> 4x4 transpose -> ds_write_b64),
// 1-step prefetch, 2 barriers/K-step. Norms: fp32 ssq in regs -> LDS atomics.
// Epilogue: per-wave 16x66 f32 scratch (overlays A) turns MFMA tiles into
// coalesced [d][w] float4 stores.

#define B_   4
#define C_   256
#define H_   128
#define W_   256
#define ND_  41
#define HW_  (H_ * W_)
#define CHW_ (C_ * HW_)
#define EPS_ 1e-6f

typedef __attribute__((ext_vector_type(4))) float f32x4;
typedef __attribute__((ext_vector_type(8))) short bf16x8;

#define ABASE 0
#define BBASE 20480            // A: 256*80
#define NBASE 44800            // B: 304*80 ends here
#define LDSZ  47040            // + 560 f32 norm area

__device__ __forceinline__ unsigned bfr(float x) {   // fp32 -> bf16 bits, RNE
  unsigned u = __builtin_bit_cast(unsigned, x);
  return (u + 0x7fffu + ((u >> 16) & 1u)) >> 16;
}

__global__ __launch_bounds__(512, 4)
void corr_mfma(const float* __restrict__ x1, const float* __restrict__ x2,
               float* __restrict__ out) {
  __shared__ __align__(16) char lds[LDSZ];

  const int tid = threadIdx.x;
  const int l   = tid & 63;
  const int v   = tid >> 6;          // wave id = staging c-quad id
  const int m   = l & 15;
  const int g   = l >> 4;

  const int r = blockIdx.x;
  const int b = r >> 7;
  const int h = r & (H_ - 1);

  const float* X1 = x1 + b * CHW_ + h * W_;
  const float* X2 = x2 + b * CHW_ + h * W_;

  // ---- prologue zero-init: norm accumulators + B pad rows 256..303 ----
  if (tid < 560) ((float*)(lds + NBASE))[tid] = 0.f;
  {
    unsigned* zp = (unsigned*)(lds + BBASE + 256 * 80);   // 48 rows * 80B
    zp[tid] = 0u;
    if (tid < 960 - 512) zp[tid + 512] = 0u;
  }

  // ---- precomputed addresses (loop-invariant) ----
  int wadr1[4];                       // staging write addrs (x1; x2 = +BBASE)
#pragma unroll
  for (int j = 0; j < 4; ++j) {
    int w = 4 * l + j;
    wadr1[j] = ABASE + w * 80 + (((v >> 1) + w) % 5) * 16 + (v & 1) * 8;
  }
  int adrA[2], adrB[2][4];            // frag read addrs
#pragma unroll
  for (int i = 0; i < 2; ++i) {
    int wt = v + 8 * i;
    int rowA = 16 * wt + m;
    adrA[i] = ABASE + rowA * 80 + ((g + rowA) % 5) * 16;
#pragma unroll
    for (int c = 0; c < 4; ++c) {
      int col = 16 * (wt + c) + m;
      adrB[i][c] = BBASE + col * 80 + ((g + col) % 5) * 16;
    }
  }

  f32x4 acc[2][4];
#pragma unroll
  for (int i = 0; i < 2; ++i)
#pragma unroll
    for (int c = 0; c < 4; ++c) acc[i][c] = (f32x4){0.f, 0.f, 0.f, 0.f};

  float ssq1[4] = {0.f, 0.f, 0.f, 0.f}, ssq2[4] = {0.f, 0.f, 0.f, 0.f};

  // ---- prefetch K-step 0 ----
  f32x4 r1[4], r2[4];
#pragma unroll
  for (int i = 0; i < 4; ++i) {
    r1[i] = *(const f32x4*)(X1 + (4 * v + i) * HW_ + 4 * l);
    r2[i] = *(const f32x4*)(X2 + (4 * v + i) * HW_ + 4 * l);
  }

  for (int ks = 0; ks < 8; ++ks) {
    __syncthreads();                  // prior compute done (iter0: zeros done)
    // ---- ssq + pack + transposed LDS write ----
#pragma unroll
    for (int j = 0; j < 4; ++j) {
#pragma unroll
      for (int i = 0; i < 4; ++i) {
        ssq1[j] += r1[i][j] * r1[i][j];
        ssq2[j] += r2[i][j] * r2[i][j];
      }
      uint2 p1, p2;
      p1.x = bfr(r1[0][j]) | (bfr(r1[1][j]) << 16);
      p1.y = bfr(r1[2][j]) | (bfr(r1[3][j]) << 16);
      p2.x = bfr(r2[0][j]) | (bfr(r2[1][j]) << 16);
      p2.y = bfr(r2[2][j]) | (bfr(r2[3][j]) << 16);
      *(uint2*)(lds + wadr1[j]) = p1;
      *(uint2*)(lds + wadr1[j] + (BBASE - ABASE)) = p2;
    }
    __syncthreads();                  // tile ready
    if (ks < 7) {                     // prefetch next K-step (hides HBM)
      const float* p1 = X1 + ((ks + 1) * 32 + 4 * v) * HW_ + 4 * l;
      const float* p2 = X2 + ((ks + 1) * 32 + 4 * v) * HW_ + 4 * l;
#pragma unroll
      for (int i = 0; i < 4; ++i) {
        r1[i] = *(const f32x4*)(p1 + i * HW_);
        r2[i] = *(const f32x4*)(p2 + i * HW_);
      }
    }
    // ---- compute: 10 ds_read_b128 + 8 MFMA ----
    bf16x8 a0 = *(const bf16x8*)(lds + adrA[0]);
    bf16x8 a1 = *(const bf16x8*)(lds + adrA[1]);
#pragma unroll
    for (int c = 0; c < 4; ++c) {
      bf16x8 b0 = *(const bf16x8*)(lds + adrB[0][c]);
      acc[0][c] = __builtin_amdgcn_mfma_f32_16x16x32_bf16(a0, b0, acc[0][c], 0, 0, 0);
    }
#pragma unroll
    for (int c = 0; c < 4; ++c) {
      bf16x8 b1 = *(const bf16x8*)(lds + adrB[1][c]);
      acc[1][c] = __builtin_amdgcn_mfma_f32_16x16x32_bf16(a1, b1, acc[1][c], 0, 0, 0);
    }
  }

  // ---- norms: LDS atomic reduce of fp32 ssq, then sqrt in place ----
  float* nsq = (float*)(lds + NBASE);
#pragma unroll
  for (int j = 0; j < 4; ++j) {
    atomicAdd(nsq + 4 * l + j, ssq1[j]);            // n1sq[w]
    atomicAdd(nsq + 256 + 4 * l + j, ssq2[j]);      // n2sq[w'] (w' < 256)
  }
  __syncthreads();
  if (tid < 256) nsq[tid] = sqrtf(nsq[tid]);
  else           nsq[tid] = sqrtf(nsq[tid]);        // n2sq[0..255]
  if (tid < 48)  nsq[512 + tid] = sqrtf(nsq[512 + tid]);   // n2sq[256..303]=0
  __syncthreads();

  // ---- epilogue: per-wave transpose -> normalize -> coalesced stores ----
  float* Sw  = (float*)(lds + v * 4224);            // 16 x 66 f32, overlays A
  float* n1s = nsq;                                 // [256]
  float* n2s = nsq + 256;                           // [304]
  const int wq = l & 3, dd = l >> 2;
#pragma unroll
  for (int i = 0; i < 2; ++i) {
    int wt = v + 8 * i;
#pragma unroll
    for (int c = 0; c < 4; ++c)
#pragma unroll
      for (int rr = 0; rr < 4; ++rr)
        Sw[(4 * g + rr) * 66 + 16 * c + m] = acc[i][c][rr];
    // wave-internal LDS RAW: compiler inserts lgkmcnt wait
#pragma unroll
    for (int p = 0; p < 3; ++p) {
      int d  = 16 * p + dd;
      int w0 = 16 * wt + 4 * wq;
      f32x4 o;
#pragma unroll
      for (int j = 0; j < 4; ++j) {
        int mm = 4 * wq + j;                        // w-local
        float dot = Sw[mm * 66 + mm + d];           // col = w-local + d
        o[j] = dot / fmaxf(n1s[w0 + j] * n2s[w0 + j + d], EPS_);
      }
      if (d <= 40)
        *(f32x4*)(out + ((b * ND_ + d) * H_ + h) * W_ + w0) = o;
    }
  }
}

extern "C" void kernel_launch(void* const* d_in, const int* in_sizes, int n_in,
                              void* d_out, int out_size, void* d_ws, size_t ws_size,
                              hipStream_t stream) {
  const float* x1 = (const float*)d_in[0];
  const float* x2 = (const float*)d_in[1];
  float* out = (float*)d_out;
  dim3 grid(B_ * H_);
  dim3 block(512);
  hipLaunchKernelGGL(corr_mfma, grid, block, 0, stream, x1, x2, out);
}